// Round 7
// baseline (219.822 us; speedup 1.0000x reference)
//
#include <hip/hip_runtime.h>
#include <hip/hip_bf16.h>
#include <stdint.h>

typedef __attribute__((ext_vector_type(4))) float f32x4;
typedef __attribute__((ext_vector_type(8))) __bf16 bf16x8;

#define NROWS 1000000

__device__ __forceinline__ bf16x8 cvt8(f32x4 a, f32x4 b) {
    bf16x8 r;
    r[0] = (__bf16)a[0]; r[1] = (__bf16)a[1];
    r[2] = (__bf16)a[2]; r[3] = (__bf16)a[3];
    r[4] = (__bf16)b[0]; r[5] = (__bf16)b[1];
    r[6] = (__bf16)b[2]; r[7] = (__bf16)b[3];
    return r;
}

// out[N,64] = relu( concat(x[nidx], ht ? x[tidx] : 0) @ W^T + b )
// MFMA mapping (v_mfma_f32_16x16x32_bf16), operand-swap:
//   A = W fragment (from LDS): lane holds W[c][k], c = ct*16+(lane&15),
//       k = ks*32+(lane>>4)*8+e
//   B = gathered x: lane holds X[r][k], r = g*16+(lane&15), same k map
//   D: col = lane&15 -> out ROW, row = (lane>>4)*4+reg -> out COL -> float4 store
// R7: depth-1 DATA pipeline. Next iteration's 8 gather instructions issue
//     before this iteration's MFMA+stores (indices prefetched depth-2), so
//     gather latency overlaps compute. W moved to 16KB LDS to fund the
//     32 in-flight VGPRs; __launch_bounds__(256,4) caps VGPR at 128.
//     Per-wave group order and store adjacency identical to R6.
__global__ __launch_bounds__(256, 4)
void heconv_mfma(const float* __restrict__ x,
                 const int* __restrict__ nidx,
                 const int* __restrict__ tidx,
                 const int* __restrict__ ht,      // bool delivered as int32
                 const float* __restrict__ W,     // [64][128]
                 const float* __restrict__ bias,  // [64]
                 float* __restrict__ out)         // [N][64]
{
    __shared__ bf16x8 wlds[4][4][64];   // [ct][ks][lane], 16 KiB

    const int tid  = threadIdx.x;
    const int lane = tid & 63;
    const int wave = tid >> 6;           // 0..3
    const int lrow = lane & 15;
    const int lkg  = lane >> 4;

    // cooperative W -> LDS (bf16 fragments, 1024 entries, 4 per thread)
    for (int e = tid; e < 1024; e += 256) {
        const int l  = e & 63;
        const int ks = (e >> 6) & 3;
        const int ct = e >> 8;
        const float* wr = W + (ct * 16 + (l & 15)) * 128 + ks * 32 + (l >> 4) * 8;
        f32x4 w0 = *(const f32x4*)(wr);
        f32x4 w1 = *(const f32x4*)(wr + 4);
        wlds[ct][ks][l] = cvt8(w0, w1);
    }
    f32x4 bfrag[4];
#pragma unroll
    for (int ct = 0; ct < 4; ++ct)
        bfrag[ct] = *(const f32x4*)(bias + ct * 16 + lkg * 4);
    __syncthreads();

    const int nGroups = NROWS / 16;           // 62500
    const int gstride = gridDim.x * 4;        // 8192 waves
    const int g0 = blockIdx.x * 4 + wave;

    const f32x4 z = {0.f, 0.f, 0.f, 0.f};

    // ---- prologue: idx(g0) -> gathers(g0); idx(g0+gs) prefetched ----
    f32x4 n0, n1, n2, n3, t0, t1, t2, t3;
    {
        const int r = g0 * 16 + lrow;
        const int ni = nidx[r];
        const int tv = tidx[r];
        const int hv = ht[r];
        const float* pn = x + (size_t)ni * 64 + lkg * 8;
        n0 = *(const f32x4*)(pn);
        n1 = *(const f32x4*)(pn + 4);
        n2 = *(const f32x4*)(pn + 32);
        n3 = *(const f32x4*)(pn + 36);
        t0 = z; t1 = z; t2 = z; t3 = z;
        if (hv) {
            const float* pt = x + (size_t)tv * 64 + lkg * 8;
            t0 = *(const f32x4*)(pt);
            t1 = *(const f32x4*)(pt + 4);
            t2 = *(const f32x4*)(pt + 32);
            t3 = *(const f32x4*)(pt + 36);
        }
    }
    int niN = 0, tiN = 0, hvN = 0;
    if (g0 + gstride < nGroups) {
        const int r = (g0 + gstride) * 16 + lrow;
        niN = nidx[r]; tiN = tidx[r]; hvN = ht[r];
    }

    for (int g = g0; g < nGroups; g += gstride) {
        const int gN = g + gstride;

        // ---- consume current gathers into MFMA fragments ----
        bf16x8 xf0 = cvt8(n0, n1);
        bf16x8 xf1 = cvt8(n2, n3);
        bf16x8 xf2 = cvt8(t0, t1);
        bf16x8 xf3 = cvt8(t2, t3);

        // ---- issue NEXT iteration's gathers (overlap with compute below) ----
        if (gN < nGroups) {
            const float* pn = x + (size_t)niN * 64 + lkg * 8;
            n0 = *(const f32x4*)(pn);
            n1 = *(const f32x4*)(pn + 4);
            n2 = *(const f32x4*)(pn + 32);
            n3 = *(const f32x4*)(pn + 36);
            t0 = z; t1 = z; t2 = z; t3 = z;
            if (hvN) {
                const float* pt = x + (size_t)tiN * 64 + lkg * 8;
                t0 = *(const f32x4*)(pt);
                t1 = *(const f32x4*)(pt + 4);
                t2 = *(const f32x4*)(pt + 32);
                t3 = *(const f32x4*)(pt + 36);
            }
        }

        // ---- prefetch idx for g + 2*gstride ----
        int ni2 = 0, ti2 = 0, hv2 = 0;
        const int g2 = g + 2 * gstride;
        if (g2 < nGroups) {
            const int r = g2 * 16 + lrow;
            ni2 = nidx[r]; ti2 = tidx[r]; hv2 = ht[r];
        }

        // ---- compute + store (W fragments from LDS) ----
        const int r = g * 16 + lrow;
        bf16x8 xf[4] = { xf0, xf1, xf2, xf3 };
#pragma unroll
        for (int ct = 0; ct < 4; ++ct) {
            f32x4 acc = bfrag[ct];
#pragma unroll
            for (int ks = 0; ks < 4; ++ks)
                acc = __builtin_amdgcn_mfma_f32_16x16x32_bf16(wlds[ct][ks][lane], xf[ks], acc, 0, 0, 0);
            f32x4 o;
            o[0] = fmaxf(acc[0], 0.f);
            o[1] = fmaxf(acc[1], 0.f);
            o[2] = fmaxf(acc[2], 0.f);
            o[3] = fmaxf(acc[3], 0.f);
            *(f32x4*)(out + (size_t)r * 64 + ct * 16 + lkg * 4) = o;
        }

        niN = ni2; tiN = ti2; hvN = hv2;
    }
}

extern "C" void kernel_launch(void* const* d_in, const int* in_sizes, int n_in,
                              void* d_out, int out_size, void* d_ws, size_t ws_size,
                              hipStream_t stream) {
    const float* x    = (const float*)d_in[0];
    const int*   ni   = (const int*)d_in[1];
    const int*   ti   = (const int*)d_in[2];
    const int*   ht   = (const int*)d_in[3];
    const float* W    = (const float*)d_in[4];
    const float* bias = (const float*)d_in[5];
    float*       out  = (float*)d_out;

    heconv_mfma<<<2048, 256, 0, stream>>>(x, ni, ti, ht, W, bias, out);
}

// Round 8
// 153.297 us; speedup vs baseline: 1.4340x; 1.4340x over previous
//
#include <hip/hip_runtime.h>
#include <hip/hip_bf16.h>
#include <stdint.h>

typedef __attribute__((ext_vector_type(4))) float f32x4;
typedef __attribute__((ext_vector_type(8))) __bf16 bf16x8;

#define NROWS 1000000

__device__ __forceinline__ bf16x8 cvt8(f32x4 a, f32x4 b) {
    bf16x8 r;
    r[0] = (__bf16)a[0]; r[1] = (__bf16)a[1];
    r[2] = (__bf16)a[2]; r[3] = (__bf16)a[3];
    r[4] = (__bf16)b[0]; r[5] = (__bf16)b[1];
    r[6] = (__bf16)b[2]; r[7] = (__bf16)b[3];
    return r;
}

// out[N,64] = relu( concat(x[nidx], ht ? x[tidx] : 0) @ W^T + b )
// MFMA mapping (v_mfma_f32_16x16x32_bf16), operand-swap:
//   A = W fragment (regs): lane holds W[c][k], c = ct*16+(lane&15), k = ks*32+(lane>>4)*8+e
//   B = gathered x:        lane holds X[r][k], r = g*16+(lane&15),  same k map
//   D: col = lane&15 -> out ROW, row = (lane>>4)*4+reg -> out COL -> float4 store
// R8: R6 + depth-1 data pipeline with sched_barrier(0) fences.
//     Cliff theory: compiler interleaving gather loads between the 4 stores of
//     an out row delays full-line coverage in L2 -> partial-line evict+refetch
//     (FETCH 192->455-595MB in R3/R5/R7). Fences pin cluster order:
//     [cvt k] | [gathers k+1] | [idx k+2, MFMA k, stores k] so stores stay
//     adjacent while gather latency overlaps the compute+store phase.
__global__ __launch_bounds__(256, 2)
void heconv_mfma(const float* __restrict__ x,
                 const int* __restrict__ nidx,
                 const int* __restrict__ tidx,
                 const int* __restrict__ ht,      // bool delivered as int32
                 const float* __restrict__ W,     // [64][128]
                 const float* __restrict__ bias,  // [64]
                 float* __restrict__ out)         // [N][64]
{
    const int lane = threadIdx.x & 63;
    const int wave = threadIdx.x >> 6;   // 0..3
    const int lrow = lane & 15;
    const int lkg  = lane >> 4;

    // W fragments in registers for the whole loop (64 VGPR)
    bf16x8 wfrag[4][4];
#pragma unroll
    for (int ct = 0; ct < 4; ++ct) {
        const float* wrow = W + (ct * 16 + lrow) * 128 + lkg * 8;
#pragma unroll
        for (int ks = 0; ks < 4; ++ks) {
            f32x4 w0 = *(const f32x4*)(wrow + ks * 32);
            f32x4 w1 = *(const f32x4*)(wrow + ks * 32 + 4);
            wfrag[ct][ks] = cvt8(w0, w1);
        }
    }
    f32x4 bfrag[4];
#pragma unroll
    for (int ct = 0; ct < 4; ++ct)
        bfrag[ct] = *(const f32x4*)(bias + ct * 16 + lkg * 4);

    const int nGroups = NROWS / 16;           // 62500
    const int gstride = gridDim.x * 4;        // 8192 waves
    const int g0 = blockIdx.x * 4 + wave;

    const f32x4 z = {0.f, 0.f, 0.f, 0.f};

    // ---- prologue: gathers(g0); idx(g0+gs) prefetched ----
    f32x4 n0, n1, n2, n3, t0, t1, t2, t3;
    if (g0 < nGroups) {
        const int r = g0 * 16 + lrow;
        const int ni = nidx[r];
        const int tv = tidx[r];
        const int hv = ht[r];
        const float* pn = x + (size_t)ni * 64 + lkg * 8;
        n0 = *(const f32x4*)(pn);
        n1 = *(const f32x4*)(pn + 4);
        n2 = *(const f32x4*)(pn + 32);
        n3 = *(const f32x4*)(pn + 36);
        t0 = z; t1 = z; t2 = z; t3 = z;
        if (hv) {
            const float* pt = x + (size_t)tv * 64 + lkg * 8;
            t0 = *(const f32x4*)(pt);
            t1 = *(const f32x4*)(pt + 4);
            t2 = *(const f32x4*)(pt + 32);
            t3 = *(const f32x4*)(pt + 36);
        }
    }
    int niN = 0, tiN = 0, hvN = 0;
    if (g0 + gstride < nGroups) {
        const int r = (g0 + gstride) * 16 + lrow;
        niN = nidx[r]; tiN = tidx[r]; hvN = ht[r];
    }

    for (int g = g0; g < nGroups; g += gstride) {
        const int gN = g + gstride;

        // ---- consume current gathers into MFMA fragments (frees n*/t*) ----
        bf16x8 xf0 = cvt8(n0, n1);
        bf16x8 xf1 = cvt8(n2, n3);
        bf16x8 xf2 = cvt8(t0, t1);
        bf16x8 xf3 = cvt8(t2, t3);

        __builtin_amdgcn_sched_barrier(0);

        // ---- issue NEXT iteration's gathers (overlap with compute below) ----
        if (gN < nGroups) {
            const float* pn = x + (size_t)niN * 64 + lkg * 8;
            n0 = *(const f32x4*)(pn);
            n1 = *(const f32x4*)(pn + 4);
            n2 = *(const f32x4*)(pn + 32);
            n3 = *(const f32x4*)(pn + 36);
            t0 = z; t1 = z; t2 = z; t3 = z;
            if (hvN) {
                const float* pt = x + (size_t)tiN * 64 + lkg * 8;
                t0 = *(const f32x4*)(pt);
                t1 = *(const f32x4*)(pt + 4);
                t2 = *(const f32x4*)(pt + 32);
                t3 = *(const f32x4*)(pt + 36);
            }
        }

        __builtin_amdgcn_sched_barrier(0);

        // ---- idx prefetch for g + 2*gstride ----
        int ni2 = 0, ti2 = 0, hv2 = 0;
        const int g2 = g + 2 * gstride;
        if (g2 < nGroups) {
            const int r = g2 * 16 + lrow;
            ni2 = nidx[r]; ti2 = tidx[r]; hv2 = ht[r];
        }

        // ---- compute + store (stores stay adjacent: only MFMAs between) ----
        const int r = g * 16 + lrow;
        bf16x8 xf[4] = { xf0, xf1, xf2, xf3 };
#pragma unroll
        for (int ct = 0; ct < 4; ++ct) {
            f32x4 acc = bfrag[ct];
#pragma unroll
            for (int ks = 0; ks < 4; ++ks)
                acc = __builtin_amdgcn_mfma_f32_16x16x32_bf16(wfrag[ct][ks], xf[ks], acc, 0, 0, 0);
            f32x4 o;
            o[0] = fmaxf(acc[0], 0.f);
            o[1] = fmaxf(acc[1], 0.f);
            o[2] = fmaxf(acc[2], 0.f);
            o[3] = fmaxf(acc[3], 0.f);
            *(f32x4*)(out + (size_t)r * 64 + ct * 16 + lkg * 4) = o;
        }

        __builtin_amdgcn_sched_barrier(0);

        niN = ni2; tiN = ti2; hvN = hv2;
    }
}

extern "C" void kernel_launch(void* const* d_in, const int* in_sizes, int n_in,
                              void* d_out, int out_size, void* d_ws, size_t ws_size,
                              hipStream_t stream) {
    const float* x    = (const float*)d_in[0];
    const int*   ni   = (const int*)d_in[1];
    const int*   ti   = (const int*)d_in[2];
    const int*   ht   = (const int*)d_in[3];
    const float* W    = (const float*)d_in[4];
    const float* bias = (const float*)d_in[5];
    float*       out  = (float*)d_out;

    heconv_mfma<<<2048, 256, 0, stream>>>(x, ni, ti, ht, W, bias, out);
}